// Round 11
// baseline (50.078 us; speedup 1.0000x reference)
//
#include <hip/hip_runtime.h>
#include <hip/hip_bf16.h>
#include <math.h>

#define B_SZ 4096
#define D_SZ 256
#define MARGIN   0.1f

typedef __attribute__((ext_vector_type(8))) __bf16 bf16x8;
typedef __attribute__((ext_vector_type(4))) float f32x4;
typedef __attribute__((ext_vector_type(8))) unsigned short u16x8;

__device__ __forceinline__ unsigned short f2bf(float f) {
    unsigned u = __float_as_uint(f);
    unsigned r = (u + 0x7FFFu + ((u >> 16) & 1u)) >> 16;   // RNE
    return (unsigned short)r;
}

__device__ __forceinline__ void gload_lds16(const void* g, void* lds) {
    __builtin_amdgcn_global_load_lds(
        (const __attribute__((address_space(1))) void*)g,
        (__attribute__((address_space(3))) void*)lds, 16, 0, 0);
}

// one wave per row: rsqrt(sumsq), write normalized bf16 feats
__global__ void norm_init_kernel(const float* __restrict__ feats,
                                 unsigned short* __restrict__ fb) {
    int row = blockIdx.x;
    int lane = threadIdx.x;
    const float4 v = *(const float4*)(feats + (size_t)row * D_SZ + lane * 4);
    float s = v.x * v.x + v.y * v.y + v.z * v.z + v.w * v.w;
#pragma unroll
    for (int m = 32; m; m >>= 1) s += __shfl_xor(s, m);
    float rinv = 1.0f / sqrtf(s);
    short4 st;
    st.x = (short)f2bf(v.x * rinv);
    st.y = (short)f2bf(v.y * rinv);
    st.z = (short)f2bf(v.z * rinv);
    st.w = (short)f2bf(v.w * rinv);
    *(short4*)(fb + (size_t)row * D_SZ + lane * 4) = st;
}

// per-class label bitmask: mask16[c*256 + t] covers labels[t*16 .. t*16+15].
// 64 classes x 4096 bits = 32 KB; row_pass then reads 2 B/thread instead of
// 64 B of raw labels (kills ~60 MB aggregate L2 traffic + 16 VGPRs).
__global__ void pack_labels(const int* __restrict__ labels,
                            unsigned short* __restrict__ mask16) {
    const int c = blockIdx.x, t = threadIdx.x;
    const int4* lp = (const int4*)(labels + t * 16);
    unsigned m = 0;
#pragma unroll
    for (int q = 0; q < 4; ++q) {
        int4 l = lp[q];
        m |= (unsigned)(l.x == c) << (q * 4 + 0);
        m |= (unsigned)(l.y == c) << (q * 4 + 1);
        m |= (unsigned)(l.z == c) << (q * 4 + 2);
        m |= (unsigned)(l.w == c) << (q * 4 + 3);
    }
    mask16[c * 256 + t] = (unsigned short)m;
}

// 128x128 tile, BK=32, THREE LDS buffers, counted-vmcnt pipeline (r9 proven):
// one barrier per K-step, stage s+2 issued post-barrier, vmcnt(4) keeps the
// next stage's loads in flight across the barrier (never drain to 0 mid-loop).
// LDS linear dest + pre-swizzled global source chunk (rule 21); fragment
// reads apply the same XOR -> 2-way (free) aliasing.
__device__ __forceinline__ void gemm_tile(const unsigned short* __restrict__ fb,
                                          unsigned short* lA0, unsigned short* lB0,
                                          int i0, int j0, int t, f32x4 acc[4][4]) {
    const int lane = t & 63, w = t >> 6;
    const int wr = w >> 1, wc = w & 1;
    const int fr = lane & 15, kg = lane >> 4;
    const int srow = lane >> 2, schunk = lane & 3;

#pragma unroll
    for (int m = 0; m < 4; ++m)
#pragma unroll
        for (int n = 0; n < 4; ++n) acc[m][n] = (f32x4){0.f, 0.f, 0.f, 0.f};

    auto stage = [&](int buf, int kc) {
#pragma unroll
        for (int half = 0; half < 2; ++half) {
            const int R0 = w * 32 + half * 16;       // 16 rows per instruction
            const int row = R0 + srow;
            const int off = ((schunk ^ ((row >> 1) & 3)) << 3);
            gload_lds16(fb + (size_t)(i0 + row) * D_SZ + kc + off,
                        lA0 + buf * (128 * 32) + R0 * 32);
            gload_lds16(fb + (size_t)(j0 + row) * D_SZ + kc + off,
                        lB0 + buf * (128 * 32) + R0 * 32);
        }
    };

    stage(0, 0);
    stage(1, 32);

#pragma unroll
    for (int s = 0; s < 8; ++s) {
        if (s < 7) asm volatile("s_waitcnt vmcnt(4)" ::: "memory");  // stage s done
        else       asm volatile("s_waitcnt vmcnt(0)" ::: "memory");
        __syncthreads();                              // all waves see buf s
        if (s + 2 < 8) stage((s + 2) % 3, (s + 2) * 32);
        const unsigned short* A  = lA0 + (s % 3) * (128 * 32);
        const unsigned short* Bp = lB0 + (s % 3) * (128 * 32);
        bf16x8 a[4], b[4];
#pragma unroll
        for (int m = 0; m < 4; ++m) {
            const int row = wr * 64 + m * 16 + fr;
            a[m] = *(const bf16x8*)(A + row * 32 + ((kg ^ ((row >> 1) & 3)) << 3));
        }
#pragma unroll
        for (int n = 0; n < 4; ++n) {
            const int row = wc * 64 + n * 16 + fr;
            b[n] = *(const bf16x8*)(Bp + row * 32 + ((kg ^ ((row >> 1) & 3)) << 3));
        }
#pragma unroll
        for (int m = 0; m < 4; ++m)
#pragma unroll
            for (int n = 0; n < 4; ++n)
                acc[m][n] = __builtin_amdgcn_mfma_f32_16x16x32_bf16(a[m], b[n], acc[m][n], 0, 0, 0);
    }
}

// Symmetric GEMM: only upper-triangular blocks (bj >= bi). Off-diagonal
// blocks additionally write the transposed tile via an LDS round-trip
// (XOR-swizzled: row ^ ((col&15)<<3), 8-elem groups stay contiguous).
__global__ __launch_bounds__(256, 4) void gemm_store_sym(const unsigned short* __restrict__ fb,
                                                         unsigned short* __restrict__ simb) {
    __shared__ unsigned short sm[3 * 128 * 32 * 2];   // 48 KB (3 bufs), reused for T
    const int t = threadIdx.x;

    int z = blockIdx.x, bi = 0;
    while (z >= 32 - bi) { z -= 32 - bi; ++bi; }
    const int bj = bi + z;
    const int i0 = bi * 128, j0 = bj * 128;

    f32x4 acc[4][4];
    gemm_tile(fb, sm, sm + 3 * 128 * 32, i0, j0, t, acc);

    const int lane = t & 63, w = t >> 6;
    const int wr = w >> 1, wc = w & 1, fr = lane & 15, kg = lane >> 4;

    // direct store (register epilogue, quarter-wave 32B-merged 2B stores)
#pragma unroll
    for (int m = 0; m < 4; ++m)
#pragma unroll
        for (int r = 0; r < 4; ++r) {
            const size_t row = i0 + wr * 64 + m * 16 + kg * 4 + r;
#pragma unroll
            for (int n = 0; n < 4; ++n)
                simb[row * B_SZ + j0 + wc * 64 + n * 16 + fr] = f2bf(acc[m][n][r]);
        }

    if (bi == bj) return;   // diagonal tile is its own transpose

    __syncthreads();        // all waves done reading gemm LDS buffers
    unsigned short* T = sm; // overlay: T[col][row^((col&15)<<3)], 128x128 bf16
#pragma unroll
    for (int m = 0; m < 4; ++m) {
        const int rowbase = wr * 64 + m * 16 + kg * 4;
#pragma unroll
        for (int n = 0; n < 4; ++n) {
            const int col = wc * 64 + n * 16 + fr;
            short4 h;
            h.x = (short)f2bf(acc[m][n][0]);
            h.y = (short)f2bf(acc[m][n][1]);
            h.z = (short)f2bf(acc[m][n][2]);
            h.w = (short)f2bf(acc[m][n][3]);
            *(short4*)(T + col * 128 + (rowbase ^ ((col & 15) << 3))) = h;
        }
    }
    __syncthreads();

    // transposed store: T row c -> simb[j0+c][i0 + r0*8 .. +7], b128 coalesced
    const int r0 = t & 15, cb = t >> 4;
#pragma unroll
    for (int p = 0; p < 8; ++p) {
        const int c = cb + p * 16;
        u16x8 v = *(const u16x8*)(T + c * 128 + 8 * (r0 ^ (c & 15)));
        *(u16x8*)(simb + (size_t)(j0 + c) * B_SZ + i0 + r0 * 8) = v;
    }
}

// one block per row: stream sim(bf16) + simw; pos/neg membership from the
// 2-byte class bitmask. Block-local min/max then exp sums from the SAME
// registers. Plain rowloss store — NO device-scope atomics/fences (r6-r8).
__global__ __launch_bounds__(256) void row_pass(const unsigned short* __restrict__ simb,
                                                const float* __restrict__ simw,
                                                const int* __restrict__ labels,
                                                const unsigned short* __restrict__ mask16,
                                                float* __restrict__ rowloss) {
    const int i = blockIdx.x, t = threadIdx.x;
    const int lane = t & 63, w = t >> 6;
    const int il = labels[i];
    const unsigned mb = mask16[il * 256 + t];   // bit e: labels[t*16+e]==il
    float sv[16], wv[16];
    {
        const u16x8* sp = (const u16x8*)(simb + (size_t)i * B_SZ + t * 16);
        u16x8 s0 = sp[0], s1 = sp[1];
#pragma unroll
        for (int e = 0; e < 8; ++e) {
            sv[e]     = __uint_as_float((unsigned)s0[e] << 16);
            sv[8 + e] = __uint_as_float((unsigned)s1[e] << 16);
        }
        const float4* wp = (const float4*)(simw + (size_t)i * B_SZ + t * 16);
#pragma unroll
        for (int q = 0; q < 4; ++q) {
            float4 wq = wp[q];
            wv[q * 4 + 0] = wq.x; wv[q * 4 + 1] = wq.y;
            wv[q * 4 + 2] = wq.z; wv[q * 4 + 3] = wq.w;
        }
    }
    float mn = INFINITY, mx = -INFINITY;
#pragma unroll
    for (int e = 0; e < 16; ++e) {
        if ((mb >> e) & 1u) mn = fminf(mn, sv[e]);
        else                mx = fmaxf(mx, sv[e]);
    }
#pragma unroll
    for (int msk = 1; msk < 64; msk <<= 1) {
        mn = fminf(mn, __shfl_xor(mn, msk));
        mx = fmaxf(mx, __shfl_xor(mx, msk));
    }
    __shared__ float smn[4], smx[4], sps[4], sns[4];
    if (lane == 0) { smn[w] = mn; smx[w] = mx; }
    __syncthreads();
    mn = fminf(fminf(smn[0], smn[1]), fminf(smn[2], smn[3]));
    mx = fmaxf(fmaxf(smx[0], smx[1]), fmaxf(smx[2], smx[3]));
    const bool hasneg = (mx != -INFINITY);
    float ps = 0.f, ns = 0.f;
#pragma unroll
    for (int e = 0; e < 16; ++e) {
        const float s = sv[e];
        if ((mb >> e) & 1u) {
            if (!hasneg || (s - MARGIN < mx))
                ps += __expf(fmaf(-2.f, s, 1.f) + wv[e]);    // exp(-2(s-.5)+w)
        } else {
            if (s + MARGIN > mn)
                ns += __expf(fmaf(40.f, s, -20.f) - wv[e]);  // exp(40(s-.5)-w)
        }
    }
#pragma unroll
    for (int msk = 1; msk < 64; msk <<= 1) {
        ps += __shfl_xor(ps, msk);
        ns += __shfl_xor(ns, msk);
    }
    if (lane == 0) { sps[w] = ps; sns[w] = ns; }
    __syncthreads();
    if (t == 0) {
        ps = sps[0] + sps[1] + sps[2] + sps[3];
        ns = sns[0] + sns[1] + sns[2] + sns[3];
        rowloss[i] = log1pf(ps) * 0.5f + log1pf(ns) * 0.025f;
    }
}

__global__ void final_big(const float* __restrict__ rowloss, float* __restrict__ out) {
    __shared__ float red[256];
    int t = threadIdx.x;
    float acc = 0.f;
    for (int i = t; i < B_SZ; i += 256) acc += rowloss[i];
    red[t] = acc;
    __syncthreads();
    for (int s = 128; s > 0; s >>= 1) {
        if (t < s) red[t] += red[t + s];
        __syncthreads();
    }
    if (t == 0) out[0] = red[0] / (float)B_SZ;
}

extern "C" void kernel_launch(void* const* d_in, const int* in_sizes, int n_in,
                              void* d_out, int out_size, void* d_ws, size_t ws_size,
                              hipStream_t stream) {
    const float* feats  = (const float*)d_in[0];
    const float* simw   = (const float*)d_in[1];
    const int*   labels = (const int*)d_in[2];
    float* out = (float*)d_out;

    char* ws = (char*)d_ws;
    float*          rowloss = (float*)ws;                            // 16 KB
    unsigned short* mask16  = (unsigned short*)(ws + B_SZ * 4);      // 32 KB
    unsigned short* fb      = (unsigned short*)(ws + B_SZ * 4 + 64 * 256 * 2);  // 2 MB
    unsigned short* simb    = (unsigned short*)(ws + B_SZ * 4 + 64 * 256 * 2
                                                + (size_t)B_SZ * D_SZ * 2);     // 32 MB

    norm_init_kernel<<<B_SZ, 64, 0, stream>>>(feats, fb);
    pack_labels<<<64, 256, 0, stream>>>(labels, mask16);
    gemm_store_sym<<<528, 256, 0, stream>>>(fb, simb);
    row_pass<<<B_SZ, 256, 0, stream>>>(simb, simw, labels, mask16, rowloss);
    final_big<<<1, 256, 0, stream>>>(rowloss, out);
}

// Round 12
// 46.358 us; speedup vs baseline: 1.0802x; 1.0802x over previous
//
#include <hip/hip_runtime.h>
#include <hip/hip_bf16.h>
#include <math.h>

#define B_SZ 4096
#define D_SZ 256
#define MARGIN   0.1f

typedef __attribute__((ext_vector_type(8))) __bf16 bf16x8;
typedef __attribute__((ext_vector_type(4))) float f32x4;
typedef __attribute__((ext_vector_type(8))) unsigned short u16x8;

__device__ __forceinline__ unsigned short f2bf(float f) {
    unsigned u = __float_as_uint(f);
    unsigned r = (u + 0x7FFFu + ((u >> 16) & 1u)) >> 16;   // RNE
    return (unsigned short)r;
}

__device__ __forceinline__ void gload_lds16(const void* g, void* lds) {
    __builtin_amdgcn_global_load_lds(
        (const __attribute__((address_space(1))) void*)g,
        (__attribute__((address_space(3))) void*)lds, 16, 0, 0);
}

// one wave per row: rsqrt(sumsq), write normalized bf16 feats
__global__ void norm_init_kernel(const float* __restrict__ feats,
                                 unsigned short* __restrict__ fb) {
    int row = blockIdx.x;
    int lane = threadIdx.x;
    const float4 v = *(const float4*)(feats + (size_t)row * D_SZ + lane * 4);
    float s = v.x * v.x + v.y * v.y + v.z * v.z + v.w * v.w;
#pragma unroll
    for (int m = 32; m; m >>= 1) s += __shfl_xor(s, m);
    float rinv = 1.0f / sqrtf(s);
    short4 st;
    st.x = (short)f2bf(v.x * rinv);
    st.y = (short)f2bf(v.y * rinv);
    st.z = (short)f2bf(v.z * rinv);
    st.w = (short)f2bf(v.w * rinv);
    *(short4*)(fb + (size_t)row * D_SZ + lane * 4) = st;
}

// 128x128 tile, BK=32, THREE LDS buffers, counted-vmcnt pipeline (r9 proven):
// one barrier per K-step, stage s+2 issued post-barrier, vmcnt(4) keeps the
// next stage's loads in flight across the barrier (never drain to 0 mid-loop).
// LDS linear dest + pre-swizzled global source chunk (rule 21); fragment
// reads apply the same XOR -> 2-way (free) aliasing.
__device__ __forceinline__ void gemm_tile(const unsigned short* __restrict__ fb,
                                          unsigned short* lA0, unsigned short* lB0,
                                          int i0, int j0, int t, f32x4 acc[4][4]) {
    const int lane = t & 63, w = t >> 6;
    const int wr = w >> 1, wc = w & 1;
    const int fr = lane & 15, kg = lane >> 4;
    const int srow = lane >> 2, schunk = lane & 3;

#pragma unroll
    for (int m = 0; m < 4; ++m)
#pragma unroll
        for (int n = 0; n < 4; ++n) acc[m][n] = (f32x4){0.f, 0.f, 0.f, 0.f};

    auto stage = [&](int buf, int kc) {
#pragma unroll
        for (int half = 0; half < 2; ++half) {
            const int R0 = w * 32 + half * 16;       // 16 rows per instruction
            const int row = R0 + srow;
            const int off = ((schunk ^ ((row >> 1) & 3)) << 3);
            gload_lds16(fb + (size_t)(i0 + row) * D_SZ + kc + off,
                        lA0 + buf * (128 * 32) + R0 * 32);
            gload_lds16(fb + (size_t)(j0 + row) * D_SZ + kc + off,
                        lB0 + buf * (128 * 32) + R0 * 32);
        }
    };

    stage(0, 0);
    stage(1, 32);

#pragma unroll
    for (int s = 0; s < 8; ++s) {
        if (s < 7) asm volatile("s_waitcnt vmcnt(4)" ::: "memory");  // stage s done
        else       asm volatile("s_waitcnt vmcnt(0)" ::: "memory");
        __syncthreads();                              // all waves see buf s
        if (s + 2 < 8) stage((s + 2) % 3, (s + 2) * 32);
        const unsigned short* A  = lA0 + (s % 3) * (128 * 32);
        const unsigned short* Bp = lB0 + (s % 3) * (128 * 32);
        bf16x8 a[4], b[4];
#pragma unroll
        for (int m = 0; m < 4; ++m) {
            const int row = wr * 64 + m * 16 + fr;
            a[m] = *(const bf16x8*)(A + row * 32 + ((kg ^ ((row >> 1) & 3)) << 3));
        }
#pragma unroll
        for (int n = 0; n < 4; ++n) {
            const int row = wc * 64 + n * 16 + fr;
            b[n] = *(const bf16x8*)(Bp + row * 32 + ((kg ^ ((row >> 1) & 3)) << 3));
        }
#pragma unroll
        for (int m = 0; m < 4; ++m)
#pragma unroll
            for (int n = 0; n < 4; ++n)
                acc[m][n] = __builtin_amdgcn_mfma_f32_16x16x32_bf16(a[m], b[n], acc[m][n], 0, 0, 0);
    }
}

// Symmetric GEMM: only upper-triangular blocks (bj >= bi). Off-diagonal
// blocks additionally write the transposed tile via an LDS round-trip
// (XOR-swizzled: row ^ ((col&15)<<3), 8-elem groups stay contiguous).
__global__ __launch_bounds__(256, 4) void gemm_store_sym(const unsigned short* __restrict__ fb,
                                                         unsigned short* __restrict__ simb) {
    __shared__ unsigned short sm[3 * 128 * 32 * 2];   // 48 KB (3 bufs), reused for T
    const int t = threadIdx.x;

    int z = blockIdx.x, bi = 0;
    while (z >= 32 - bi) { z -= 32 - bi; ++bi; }
    const int bj = bi + z;
    const int i0 = bi * 128, j0 = bj * 128;

    f32x4 acc[4][4];
    gemm_tile(fb, sm, sm + 3 * 128 * 32, i0, j0, t, acc);

    const int lane = t & 63, w = t >> 6;
    const int wr = w >> 1, wc = w & 1, fr = lane & 15, kg = lane >> 4;

    // direct store (register epilogue, quarter-wave 32B-merged 2B stores)
#pragma unroll
    for (int m = 0; m < 4; ++m)
#pragma unroll
        for (int r = 0; r < 4; ++r) {
            const size_t row = i0 + wr * 64 + m * 16 + kg * 4 + r;
#pragma unroll
            for (int n = 0; n < 4; ++n)
                simb[row * B_SZ + j0 + wc * 64 + n * 16 + fr] = f2bf(acc[m][n][r]);
        }

    if (bi == bj) return;   // diagonal tile is its own transpose

    __syncthreads();        // all waves done reading gemm LDS buffers
    unsigned short* T = sm; // overlay: T[col][row^((col&15)<<3)], 128x128 bf16
#pragma unroll
    for (int m = 0; m < 4; ++m) {
        const int rowbase = wr * 64 + m * 16 + kg * 4;
#pragma unroll
        for (int n = 0; n < 4; ++n) {
            const int col = wc * 64 + n * 16 + fr;
            short4 h;
            h.x = (short)f2bf(acc[m][n][0]);
            h.y = (short)f2bf(acc[m][n][1]);
            h.z = (short)f2bf(acc[m][n][2]);
            h.w = (short)f2bf(acc[m][n][3]);
            *(short4*)(T + col * 128 + (rowbase ^ ((col & 15) << 3))) = h;
        }
    }
    __syncthreads();

    // transposed store: T row c -> simb[j0+c][i0 + r0*8 .. +7], b128 coalesced
    const int r0 = t & 15, cb = t >> 4;
#pragma unroll
    for (int p = 0; p < 8; ++p) {
        const int c = cb + p * 16;
        u16x8 v = *(const u16x8*)(T + c * 128 + 8 * (r0 ^ (c & 15)));
        *(u16x8*)(simb + (size_t)(j0 + c) * B_SZ + i0 + r0 * 8) = v;
    }
}

// one block per row (r5/r9 proven fast): stream sim(bf16) + simw + labels,
// block-local min/max then exp sums from the SAME registers. Plain rowloss
// store — NO device-scope atomics/fences (r6-r8 post-mortem).
__global__ __launch_bounds__(256) void row_pass(const unsigned short* __restrict__ simb,
                                                const float* __restrict__ simw,
                                                const int* __restrict__ labels,
                                                float* __restrict__ rowloss) {
    const int i = blockIdx.x, t = threadIdx.x;
    const int lane = t & 63, w = t >> 6;
    const int il = labels[i];
    float sv[16], wv[16];
    int lj[16];
    {
        const u16x8* sp = (const u16x8*)(simb + (size_t)i * B_SZ + t * 16);
        u16x8 s0 = sp[0], s1 = sp[1];
#pragma unroll
        for (int e = 0; e < 8; ++e) {
            sv[e]     = __uint_as_float((unsigned)s0[e] << 16);
            sv[8 + e] = __uint_as_float((unsigned)s1[e] << 16);
        }
        const float4* wp = (const float4*)(simw + (size_t)i * B_SZ + t * 16);
#pragma unroll
        for (int q = 0; q < 4; ++q) {
            float4 wq = wp[q];
            wv[q * 4 + 0] = wq.x; wv[q * 4 + 1] = wq.y;
            wv[q * 4 + 2] = wq.z; wv[q * 4 + 3] = wq.w;
        }
        const int4* lp = (const int4*)(labels + t * 16);
#pragma unroll
        for (int q = 0; q < 4; ++q) {
            int4 lq = lp[q];
            lj[q * 4 + 0] = lq.x; lj[q * 4 + 1] = lq.y;
            lj[q * 4 + 2] = lq.z; lj[q * 4 + 3] = lq.w;
        }
    }
    float mn = INFINITY, mx = -INFINITY;
#pragma unroll
    for (int e = 0; e < 16; ++e) {
        if (lj[e] == il) mn = fminf(mn, sv[e]);
        else             mx = fmaxf(mx, sv[e]);
    }
#pragma unroll
    for (int msk = 1; msk < 64; msk <<= 1) {
        mn = fminf(mn, __shfl_xor(mn, msk));
        mx = fmaxf(mx, __shfl_xor(mx, msk));
    }
    __shared__ float smn[4], smx[4], sps[4], sns[4];
    if (lane == 0) { smn[w] = mn; smx[w] = mx; }
    __syncthreads();
    mn = fminf(fminf(smn[0], smn[1]), fminf(smn[2], smn[3]));
    mx = fmaxf(fmaxf(smx[0], smx[1]), fmaxf(smx[2], smx[3]));
    const bool hasneg = (mx != -INFINITY);
    float ps = 0.f, ns = 0.f;
#pragma unroll
    for (int e = 0; e < 16; ++e) {
        const float s = sv[e];
        if (lj[e] == il) {
            if (!hasneg || (s - MARGIN < mx))
                ps += __expf(fmaf(-2.f, s, 1.f) + wv[e]);    // exp(-2(s-.5)+w)
        } else {
            if (s + MARGIN > mn)
                ns += __expf(fmaf(40.f, s, -20.f) - wv[e]);  // exp(40(s-.5)-w)
        }
    }
#pragma unroll
    for (int msk = 1; msk < 64; msk <<= 1) {
        ps += __shfl_xor(ps, msk);
        ns += __shfl_xor(ns, msk);
    }
    if (lane == 0) { sps[w] = ps; sns[w] = ns; }
    __syncthreads();
    if (t == 0) {
        ps = sps[0] + sps[1] + sps[2] + sps[3];
        ns = sns[0] + sns[1] + sns[2] + sns[3];
        rowloss[i] = log1pf(ps) * 0.5f + log1pf(ns) * 0.025f;
    }
}

__global__ void final_big(const float* __restrict__ rowloss, float* __restrict__ out) {
    __shared__ float red[256];
    int t = threadIdx.x;
    float acc = 0.f;
    for (int i = t; i < B_SZ; i += 256) acc += rowloss[i];
    red[t] = acc;
    __syncthreads();
    for (int s = 128; s > 0; s >>= 1) {
        if (t < s) red[t] += red[t + s];
        __syncthreads();
    }
    if (t == 0) out[0] = red[0] / (float)B_SZ;
}

extern "C" void kernel_launch(void* const* d_in, const int* in_sizes, int n_in,
                              void* d_out, int out_size, void* d_ws, size_t ws_size,
                              hipStream_t stream) {
    const float* feats  = (const float*)d_in[0];
    const float* simw   = (const float*)d_in[1];
    const int*   labels = (const int*)d_in[2];
    float* out = (float*)d_out;

    char* ws = (char*)d_ws;
    float*    rowloss = (float*)ws;                                  // 16 KB
    unsigned short* fb   = (unsigned short*)(ws + B_SZ * 4);         // 2 MB
    unsigned short* simb = (unsigned short*)(ws + B_SZ * 4 + (size_t)B_SZ * D_SZ * 2); // 32 MB

    norm_init_kernel<<<B_SZ, 64, 0, stream>>>(feats, fb);
    gemm_store_sym<<<528, 256, 0, stream>>>(fb, simb);
    row_pass<<<B_SZ, 256, 0, stream>>>(simb, simw, labels, rowloss);
    final_big<<<1, 256, 0, stream>>>(rowloss, out);
}